// Round 4
// baseline (141.169 us; speedup 1.0000x reference)
//
#include <hip/hip_runtime.h>
#include <math.h>

constexpr int cB = 8, cN = 1600, cT = 64, cH = 32, cHEADS = 4, cHD = 8, cFC = 16, cHOR = 12;
constexpr int cROWS = cB * cN; // 12800

__device__ __forceinline__ float sigmoidf_(float x) { return 1.0f / (1.0f + __expf(-x)); }
__device__ __forceinline__ float tanhf_(float x) {
    float xc = fminf(fmaxf(x, -15.0f), 15.0f);
    float e = __expf(-2.0f * xc);
    return (1.0f - e) / (1.0f + e);
}
__device__ __forceinline__ float elu1_(float x) { return (x > 0.0f) ? (x + 1.0f) : __expf(x); }

// K0: transpose fp_w -> wT[ct*32+h]; zero feat accumulator and kv accumulator.
__global__ __launch_bounds__(256) void k0_init(const float* __restrict__ fp_w,
                                               float* __restrict__ wT,
                                               float* __restrict__ feat_r,
                                               float* __restrict__ kv) {
    int i = blockIdx.x * 256 + threadIdx.x;   // 0..409599
    feat_r[i] = 0.0f;
    if (i < 32768) {
        int h = i >> 10, ct = i & 1023;
        wT[ct * cH + h] = fp_w[i];
    }
    if (i < cB * cHEADS * 64) kv[i] = 0.0f;
}

// kA_feat: conv+BN+ReLU+pointwise+BN+ReLU + K-slice of feat GEMM.
// Grid = 800 = 200 row-groups x 4 K-slices. Block = 256 thr = 4 waves, 1 channel/wave.
__global__ __launch_bounds__(256, 4) void kA_feat(
    const float* __restrict__ x,
    const float* __restrict__ dw_w, const float* __restrict__ dw_b,
    const float* __restrict__ bn1_g, const float* __restrict__ bn1_b,
    const float* __restrict__ bn1_m, const float* __restrict__ bn1_v,
    const float* __restrict__ pw_w, const float* __restrict__ pw_b,
    const float* __restrict__ bn2_g, const float* __restrict__ bn2_b,
    const float* __restrict__ bn2_m, const float* __restrict__ bn2_v,
    const float* __restrict__ wT,
    float* __restrict__ feat_r)
{
    __shared__ float red[4 * 2080]; // [w][h*65+lane], 33280 B -> 4 blocks/CU

    const int tid = threadIdx.x;
    const int lane = tid & 63;
    const int w = __builtin_amdgcn_readfirstlane(tid >> 6); // 0..3
    const int rg = blockIdx.x >> 2;
    const int ks = blockIdx.x & 3;
    const int c = ks * 4 + w;       // uniform channel 0..15
    const int r0 = rg * 64;
    const int b = r0 / cN;          // uniform (64 | 1600)
    const int n0 = r0 - b * cN;
    const float* xb = x + (size_t)b * cT * cN + (n0 + lane);

    // depthwise conv + BN1 + ReLU (redundant x4 waves; ~300 ops, acceptable)
    const float inv1 = bn1_g[0] * rsqrtf(bn1_v[0] + 1e-5f);
    const float A = inv1;
    const float C = (dw_b[0] - bn1_m[0]) * inv1 + bn1_b[0];
    const float w0 = dw_w[0], w1 = dw_w[1], w2 = dw_w[2];

    float y1[cT];
    float xm = 0.0f, xc = xb[0];
    #pragma unroll
    for (int t = 0; t < cT; ++t) {
        float xp = (t + 1 < cT) ? xb[(size_t)(t + 1) * cN] : 0.0f;
        float s = w0 * xm + w1 * xc + w2 * xp;
        y1[t] = fmaxf(0.0f, fmaf(s, A, C));
        xm = xc; xc = xp;
    }

    // pointwise channel c + BN2 + ReLU + GEMM slice
    const float inv2 = bn2_g[c] * rsqrtf(bn2_v[c] + 1e-5f);
    const float a2 = pw_w[c] * inv2;
    const float c2 = (pw_b[c] - bn2_m[c]) * inv2 + bn2_b[c];
    const float* wrow = wT + (size_t)(c * cT) * cH;

    float acc[cH];
    #pragma unroll
    for (int h = 0; h < cH; ++h) acc[h] = 0.0f;
    #pragma unroll
    for (int t = 0; t < cT; ++t) {
        const float y2 = fmaxf(0.0f, fmaf(a2, y1[t], c2));
        #pragma unroll
        for (int h = 0; h < cH; ++h)
            acc[h] = fmaf(y2, wrow[t * cH + h], acc[h]);
    }

    #pragma unroll
    for (int h = 0; h < cH; ++h) red[w * 2080 + h * 65 + lane] = acc[h];
    __syncthreads();

    #pragma unroll
    for (int o2 = 0; o2 < 8; ++o2) {
        const int o = tid + o2 * 256;
        const int h = o >> 6, rp = o & 63;
        const float s = red[0 * 2080 + h * 65 + rp] + red[1 * 2080 + h * 65 + rp] +
                        red[2 * 2080 + h * 65 + rp] + red[3 * 2080 + h * 65 + rp];
        atomicAdd(&feat_r[(size_t)(r0 + rp) * cH + h], s);
    }
}

// K2: qkv + elu+1 + z + block-partial kv reduction. 8 lanes/row, 32 rows/block, grid 400.
__global__ __launch_bounds__(256) void k2_qkv(
    const float* __restrict__ feat_r, const float* __restrict__ fp_b,
    const float* __restrict__ lo_w, const float* __restrict__ lo_b,
    const float* __restrict__ hi_w, const float* __restrict__ hi_b,
    float* __restrict__ qe, float* __restrict__ zz, float* __restrict__ kvout)
{
    __shared__ float lbuf[32][25];
    __shared__ float ske[32][33];
    __shared__ float svv[32][33];

    const int tid = threadIdx.x;
    const int r = tid >> 3;      // row in block 0..31
    const int j = tid & 7;       // octet lane
    const int row = blockIdx.x * 32 + r;
    const int b = __builtin_amdgcn_readfirstlane((blockIdx.x * 32) / cN); // uniform
    const int n = row - b * cN;

    float f[cH];
    const float4* fr4 = (const float4*)(feat_r + (size_t)row * cH);
    #pragma unroll
    for (int q = 0; q < 8; ++q) {
        float4 v = fr4[q];
        f[4*q]   = v.x + fp_b[4*q];
        f[4*q+1] = v.y + fp_b[4*q+1];
        f[4*q+2] = v.z + fp_b[4*q+2];
        f[4*q+3] = v.w + fp_b[4*q+3];
    }

    float lo0 = lo_b[j], lo1 = lo_b[j+8], lo2 = lo_b[j+16];
    #pragma unroll
    for (int i = 0; i < cH; ++i) {
        lo0 = fmaf(f[i], lo_w[j * cH + i], lo0);
        lo1 = fmaf(f[i], lo_w[(j+8) * cH + i], lo1);
        lo2 = fmaf(f[i], lo_w[(j+16) * cH + i], lo2);
    }
    lbuf[r][j] = lo0; lbuf[r][j+8] = lo1; lbuf[r][j+16] = lo2;
    __syncthreads();
    float lof[24];
    #pragma unroll
    for (int i = 0; i < 24; ++i) lof[i] = lbuf[r][i];

    float qv[4], kv4[4], vv4[4];
    #pragma unroll
    for (int m = 0; m < 4; ++m) {
        const int oi = m * 8 + j;
        float sq = hi_b[oi], sk = hi_b[32 + oi], sv = hi_b[64 + oi];
        #pragma unroll
        for (int i = 0; i < 24; ++i) {
            sq = fmaf(lof[i], hi_w[oi * 24 + i], sq);
            sk = fmaf(lof[i], hi_w[(32 + oi) * 24 + i], sk);
            sv = fmaf(lof[i], hi_w[(64 + oi) * 24 + i], sv);
        }
        qv[m] = elu1_(sq);
        kv4[m] = elu1_(sk);
        vv4[m] = sv;
    }

    // z: per-head sums across octet lanes
    float s0 = kv4[0], s1 = kv4[1], s2 = kv4[2], s3 = kv4[3];
    #pragma unroll
    for (int off = 1; off < 8; off <<= 1) {
        s0 += __shfl_xor(s0, off, 8);
        s1 += __shfl_xor(s1, off, 8);
        s2 += __shfl_xor(s2, off, 8);
        s3 += __shfl_xor(s3, off, 8);
    }
    if (j < 4) {
        float sv = (j == 0) ? s0 : ((j == 1) ? s1 : ((j == 2) ? s2 : s3));
        zz[(size_t)(b * cHEADS + j) * cN + n] = 1.0f / (sv + 1e-8f);
    }

    #pragma unroll
    for (int m = 0; m < 4; ++m) {
        qe[(size_t)row * cH + m * 8 + j] = qv[m];
        ske[r][m * 8 + j] = kv4[m];
        svv[r][m * 8 + j] = vv4[m];
    }
    __syncthreads();

    // block-partial kv: thread = (head m, d, e); 32-row reduction
    {
        const int m = tid >> 6, d = (tid >> 3) & 7, e = tid & 7;
        float s = 0.0f;
        #pragma unroll
        for (int rr = 0; rr < 32; ++rr)
            s = fmaf(ske[rr][m * 8 + d], svv[rr][m * 8 + e], s);
        atomicAdd(&kvout[(size_t)(b * cHEADS + m) * 64 + d * 8 + e], s);
    }
}

// K4: att_out + projections + GRU + blend. 8 lanes/row, 32 rows/block, grid 400.
__global__ __launch_bounds__(256) void k4_final(
    const float* __restrict__ x,
    const float* __restrict__ feat_r, const float* __restrict__ fp_b,
    const float* __restrict__ qe,
    const float* __restrict__ zz, const float* __restrict__ kv,
    const float* __restrict__ out_lo_w, const float* __restrict__ out_lo_b,
    const float* __restrict__ out_hi_w, const float* __restrict__ out_hi_b,
    const float* __restrict__ hp_w, const float* __restrict__ hp_b,
    const float* __restrict__ gru_wih, const float* __restrict__ gru_whh,
    const float* __restrict__ gru_bih, const float* __restrict__ gru_bhh,
    const float* __restrict__ op_w, const float* __restrict__ op_b,
    const float* __restrict__ log_decay,
    const float* __restrict__ rg1_w, const float* __restrict__ rg1_b,
    const float* __restrict__ rg2_w, const float* __restrict__ rg2_b,
    const float* __restrict__ log_reg,
    float* __restrict__ out)
{
    __shared__ float sA[32][36];
    __shared__ float sB[32][36];
    __shared__ float sC[32][36];

    const int tid = threadIdx.x;
    const int r = tid >> 3;
    const int j = tid & 7;
    const int row = blockIdx.x * 32 + r;
    const int b = __builtin_amdgcn_readfirstlane((blockIdx.x * 32) / cN);
    const int n = row - b * cN;

    {
        const float4* q4 = (const float4*)(qe + (size_t)row * cH);
        float4 v = q4[j];
        *(float4*)&sA[r][4 * j] = v;
    }
    __syncthreads();

    float o_m[4];
    #pragma unroll
    for (int m = 0; m < 4; ++m) {
        const float z = zz[(size_t)(b * cHEADS + m) * cN + n];
        const float* kvp = kv + (size_t)(b * cHEADS + m) * 64;
        float s = 0.0f;
        #pragma unroll
        for (int d = 0; d < 8; ++d)
            s = fmaf(sA[r][m * 8 + d], kvp[d * 8 + j], s);
        o_m[m] = s * z;
    }
    #pragma unroll
    for (int m = 0; m < 4; ++m) sB[r][m * 8 + j] = o_m[m];
    __syncthreads();

    float lo_j = out_lo_b[j];
    #pragma unroll
    for (int i = 0; i < cH; ++i)
        lo_j = fmaf(sB[r][i], out_lo_w[j * cH + i], lo_j);

    float lof[8];
    #pragma unroll
    for (int i = 0; i < 8; ++i) lof[i] = __shfl(lo_j, i, 8);

    float f2_m[4];
    #pragma unroll
    for (int m = 0; m < 4; ++m) {
        const int i = m * 8 + j;
        float s = out_hi_b[i];
        #pragma unroll
        for (int q = 0; q < 8; ++q) s = fmaf(lof[q], out_hi_w[i * 8 + q], s);
        f2_m[m] = feat_r[(size_t)row * cH + i] + fp_b[i] + s;
        sC[r][i] = f2_m[m];
    }
    __syncthreads();

    float h0_j = hp_b[j], g1_j = rg1_b[j];
    #pragma unroll
    for (int i = 0; i < cH; ++i) {
        float fv = sC[r][i];
        h0_j = fmaf(fv, hp_w[j * cH + i], h0_j);
        g1_j = fmaf(fv, rg1_w[j * cH + i], g1_j);
    }
    g1_j = fmaxf(0.0f, g1_j);

    float g1f[8];
    #pragma unroll
    for (int i = 0; i < 8; ++i) g1f[i] = __shfl(g1_j, i, 8);

    float ga = rg2_b[j], gb_ = rg2_b[8 + (j & 3)];
    #pragma unroll
    for (int q = 0; q < 8; ++q) {
        ga = fmaf(g1f[q], rg2_w[j * 8 + q], ga);
        gb_ = fmaf(g1f[q], rg2_w[(8 + (j & 3)) * 8 + q], gb_);
    }
    const float gate_a = sigmoidf_(ga);
    const float gate_b = sigmoidf_(gb_);

    const float last = x[(size_t)b * cT * cN + (size_t)(cT - 1) * cN + n];

    float whh_r[8], whh_z[8], whh_n[8], opw[8];
    #pragma unroll
    for (int i = 0; i < 8; ++i) {
        whh_r[i] = gru_whh[j * 8 + i];
        whh_z[i] = gru_whh[(8 + j) * 8 + i];
        whh_n[i] = gru_whh[(16 + j) * 8 + i];
        opw[i] = op_w[i];
    }
    const float wih_r = gru_wih[j], wih_z = gru_wih[8 + j], wih_n = gru_wih[16 + j];
    const float bih_r = gru_bih[j], bih_z = gru_bih[8 + j], bih_n = gru_bih[16 + j];
    const float bhh_r = gru_bhh[j], bhh_z = gru_bhh[8 + j], bhh_n = gru_bhh[16 + j];
    const float opb = op_b[0];

    float h_full[8];
    #pragma unroll
    for (int i = 0; i < 8; ++i) h_full[i] = __shfl(h0_j, i, 8);
    float h_own = h0_j;
    float cur = last;
    float po_a = 0.0f, po_b = 0.0f;

    #pragma unroll
    for (int s = 0; s < cHOR; ++s) {
        float ghr = bhh_r, ghz = bhh_z, ghn = bhh_n;
        #pragma unroll
        for (int i = 0; i < 8; ++i) {
            ghr = fmaf(h_full[i], whh_r[i], ghr);
            ghz = fmaf(h_full[i], whh_z[i], ghz);
            ghn = fmaf(h_full[i], whh_n[i], ghn);
        }
        const float r_ = sigmoidf_(fmaf(wih_r, cur, bih_r) + ghr);
        const float zg = sigmoidf_(fmaf(wih_z, cur, bih_z) + ghz);
        const float nn = tanhf_(fmaf(wih_n, cur, bih_n) + r_ * ghn);
        const float hn = (1.0f - zg) * nn + zg * h_own;
        h_own = hn;
        #pragma unroll
        for (int i = 0; i < 8; ++i) h_full[i] = __shfl(hn, i, 8);
        float p = opb;
        #pragma unroll
        for (int i = 0; i < 8; ++i) p = fmaf(h_full[i], opw[i], p);
        po_a = (s == j) ? p : po_a;
        po_b = (s == 8 + j) ? p : po_b;
        cur = p;
    }

    const float dk = __expf(log_decay[0]);
    float* orow = out + (size_t)row * 12;
    orow[j] = gate_a * po_a + (1.0f - gate_a) * last * __expf(-dk * (float)(j + 1));
    if (j < 4)
        orow[8 + j] = gate_b * po_b + (1.0f - gate_b) * last * __expf(-dk * (float)(j + 9));

    if (row == 0 && j == 0)
        out[(size_t)cROWS * 12] = __expf(log_reg[0]) * (1.0f / (float)cN);
}

extern "C" void kernel_launch(void* const* d_in, const int* in_sizes, int n_in,
                              void* d_out, int out_size, void* d_ws, size_t ws_size,
                              hipStream_t stream)
{
    const float* x      = (const float*)d_in[0];
    const float* dw_w   = (const float*)d_in[1];
    const float* dw_b   = (const float*)d_in[2];
    const float* bn1_g  = (const float*)d_in[3];
    const float* bn1_b  = (const float*)d_in[4];
    const float* bn1_m  = (const float*)d_in[5];
    const float* bn1_v  = (const float*)d_in[6];
    const float* pw_w   = (const float*)d_in[7];
    const float* pw_b   = (const float*)d_in[8];
    const float* bn2_g  = (const float*)d_in[9];
    const float* bn2_b  = (const float*)d_in[10];
    const float* bn2_m  = (const float*)d_in[11];
    const float* bn2_v  = (const float*)d_in[12];
    const float* fp_w   = (const float*)d_in[13];
    const float* fp_b   = (const float*)d_in[14];
    const float* lo_w   = (const float*)d_in[15];
    const float* lo_b   = (const float*)d_in[16];
    const float* hi_w   = (const float*)d_in[17];
    const float* hi_b   = (const float*)d_in[18];
    const float* olo_w  = (const float*)d_in[19];
    const float* olo_b  = (const float*)d_in[20];
    const float* ohi_w  = (const float*)d_in[21];
    const float* ohi_b  = (const float*)d_in[22];
    // d_in[23]=u, d_in[24]=v dead (softmax row-sums == 1 -> mean|attn| == 1/N)
    const float* log_reg = (const float*)d_in[25];
    const float* hp_w   = (const float*)d_in[26];
    const float* hp_b   = (const float*)d_in[27];
    const float* gru_wih = (const float*)d_in[28];
    const float* gru_whh = (const float*)d_in[29];
    const float* gru_bih = (const float*)d_in[30];
    const float* gru_bhh = (const float*)d_in[31];
    const float* op_w   = (const float*)d_in[32];
    const float* op_b   = (const float*)d_in[33];
    const float* log_decay = (const float*)d_in[34];
    const float* rg1_w  = (const float*)d_in[35];
    const float* rg1_b  = (const float*)d_in[36];
    const float* rg2_w  = (const float*)d_in[37];
    const float* rg2_b  = (const float*)d_in[38];

    float* ws     = (float*)d_ws;
    float* wT     = ws;                    // 32768
    float* feat_r = wT + 32768;            // 409600  [row*32+h] (accumulator, no fp_b)
    float* qe     = feat_r + 409600;       // 409600  [row*32]
    float* zz     = qe + 409600;           // 51200   [(b*4+h)*1600+n]
    float* kv     = zz + 51200;            // 2048

    k0_init<<<1600, 256, 0, stream>>>(fp_w, wT, feat_r, kv);
    kA_feat<<<800, 256, 0, stream>>>(x, dw_w, dw_b, bn1_g, bn1_b, bn1_m, bn1_v,
                                     pw_w, pw_b, bn2_g, bn2_b, bn2_m, bn2_v,
                                     wT, feat_r);
    k2_qkv<<<cROWS / 32, 256, 0, stream>>>(feat_r, fp_b, lo_w, lo_b, hi_w, hi_b,
                                           qe, zz, kv);
    k4_final<<<cROWS / 32, 256, 0, stream>>>(x, feat_r, fp_b, qe, zz, kv,
                                             olo_w, olo_b, ohi_w, ohi_b,
                                             hp_w, hp_b, gru_wih, gru_whh, gru_bih, gru_bhh,
                                             op_w, op_b, log_decay,
                                             rg1_w, rg1_b, rg2_w, rg2_b, log_reg,
                                             (float*)d_out);
}

// Round 5
// 52.158 us; speedup vs baseline: 2.7066x; 2.7066x over previous
//
#include <hip/hip_runtime.h>
#include <math.h>

constexpr int cB = 8, cN = 1600, cT = 64, cH = 32, cHEADS = 4, cHD = 8, cFC = 16, cHOR = 12;
constexpr int cROWS = cB * cN; // 12800

typedef __attribute__((ext_vector_type(8))) short short8;
typedef __attribute__((ext_vector_type(4))) float f32x4;

__device__ __forceinline__ float sigmoidf_(float x) { return 1.0f / (1.0f + __expf(-x)); }
__device__ __forceinline__ float tanhf_(float x) {
    float xc = fminf(fmaxf(x, -15.0f), 15.0f);
    float e = __expf(-2.0f * xc);
    return (1.0f - e) / (1.0f + e);
}
__device__ __forceinline__ float elu1_(float x) { return (x > 0.0f) ? (x + 1.0f) : __expf(x); }
__device__ __forceinline__ short f2bf(float f) {   // RNE fp32->bf16
    unsigned u = __float_as_uint(f);
    u = (u + 0x7fffu + ((u >> 16) & 1u)) >> 16;
    return (short)u;
}

// K0: fp_w [32][1024] fp32 -> bf16 (same layout = B^T fragments); zero kv.
__global__ __launch_bounds__(256) void k0_init(const float* __restrict__ fp_w,
                                               unsigned short* __restrict__ wbt,
                                               float* __restrict__ kv) {
    int i = blockIdx.x * 256 + threadIdx.x;   // 0..32767
    wbt[i] = (unsigned short)f2bf(fp_w[i]);
    if (i < cB * cHEADS * 64) kv[i] = 0.0f;
}

// kFeat: conv+BN+ReLU+pointwise+BN+ReLU fused into an MFMA GEMM.
// Grid = 1600 = 800 row-groups(16 rows) x 2 K-halves. Block = 1 wave (64 thr).
// A = y2[16 rows][512 K] built on the fly in registers; B = wbt bf16 (global, L2-hot).
__global__ __launch_bounds__(64) void kFeat(
    const float* __restrict__ x,
    const float* __restrict__ dw_w, const float* __restrict__ dw_b,
    const float* __restrict__ bn1_g, const float* __restrict__ bn1_b,
    const float* __restrict__ bn1_m, const float* __restrict__ bn1_v,
    const float* __restrict__ pw_w, const float* __restrict__ pw_b,
    const float* __restrict__ bn2_g, const float* __restrict__ bn2_b,
    const float* __restrict__ bn2_m, const float* __restrict__ bn2_v,
    const unsigned short* __restrict__ wbt,
    float* __restrict__ feat_p)   // [2][cROWS][32]
{
    __shared__ float y1s[16 * 65];

    const int l = threadIdx.x;
    const int rg = blockIdx.x >> 1;
    const int hk = blockIdx.x & 1;
    const int r0 = rg * 16;
    const int b = r0 / cN;          // uniform (16 | 1600)
    const int n0 = r0 - b * cN;

    const float inv1 = bn1_g[0] * rsqrtf(bn1_v[0] + 1e-5f);
    const float A = inv1;
    const float C = (dw_b[0] - bn1_m[0]) * inv1 + bn1_b[0];
    const float w0 = dw_w[0], w1 = dw_w[1], w2 = dw_w[2];

    // y1 for the 16 rows: lane computes row=l&15, t-range (l>>4)*16..+15
    {
        const int rr = l & 15;
        const int t0 = (l >> 4) * 16;
        const float* xp = x + (size_t)b * cT * cN + (n0 + rr);
        float xv[18];
        #pragma unroll
        for (int q = 0; q < 18; ++q) {
            int t = t0 - 1 + q;
            xv[q] = (t >= 0 && t < cT) ? xp[(size_t)t * cN] : 0.0f;
        }
        #pragma unroll
        for (int q = 0; q < 16; ++q) {
            float s = w0 * xv[q] + w1 * xv[q + 1] + w2 * xv[q + 2];
            y1s[rr * 65 + t0 + q] = fmaxf(0.0f, fmaf(s, A, C));
        }
    }
    __syncthreads();

    // per-K-half channel affines: c = hk*8 + cc
    float a2r[8], c2r[8];
    #pragma unroll
    for (int cc = 0; cc < 8; ++cc) {
        const int c = hk * 8 + cc;
        const float inv2 = bn2_g[c] * rsqrtf(bn2_v[c] + 1e-5f);
        a2r[cc] = pw_w[c] * inv2;
        c2r[cc] = (pw_b[c] - bn2_m[c]) * inv2 + bn2_b[c];
    }

    // lane's 16 y1 values: k = kk*32 + off + i  ->  t = (kk&1)*32 + off + i
    const int rr = l & 15;
    const int off = (l >> 4) * 8;
    float y1r[16];
    #pragma unroll
    for (int p = 0; p < 8; ++p) {
        y1r[p]     = y1s[rr * 65 + off + p];
        y1r[8 + p] = y1s[rr * 65 + 32 + off + p];
    }

    const unsigned short* b0p = wbt + (size_t)(l & 15) * 1024 + hk * 512 + off;
    const unsigned short* b1p = wbt + (size_t)(16 + (l & 15)) * 1024 + hk * 512 + off;

    f32x4 acc0 = {0.f, 0.f, 0.f, 0.f};
    f32x4 acc1 = {0.f, 0.f, 0.f, 0.f};

    #pragma unroll
    for (int kk = 0; kk < 16; ++kk) {
        const float a2 = a2r[kk >> 1], c2v = c2r[kk >> 1];
        short8 af;
        #pragma unroll
        for (int i = 0; i < 8; ++i) {
            const float y2 = fmaxf(0.0f, fmaf(a2, y1r[(kk & 1) * 8 + i], c2v));
            af[i] = f2bf(y2);
        }
        const short8 bf0 = *(const short8*)(b0p + kk * 32);
        const short8 bf1 = *(const short8*)(b1p + kk * 32);
        acc0 = __builtin_amdgcn_mfma_f32_16x16x32_bf16(af, bf0, acc0, 0, 0, 0);
        acc1 = __builtin_amdgcn_mfma_f32_16x16x32_bf16(af, bf1, acc1, 0, 0, 0);
    }

    // C/D layout: col = l&15, row = (l>>4)*4 + reg  [verified m89]
    float* fp = feat_p + (size_t)hk * ((size_t)cROWS * cH);
    const int col = l & 15;
    const int rbase = r0 + (l >> 4) * 4;
    #pragma unroll
    for (int reg = 0; reg < 4; ++reg) {
        fp[(size_t)(rbase + reg) * cH + col]      = acc0[reg];
        fp[(size_t)(rbase + reg) * cH + 16 + col] = acc1[reg];
    }
}

// K2: sum feat halves (+fp_b) -> feat_c; qkv + elu+1 + z + block-partial kv.
__global__ __launch_bounds__(256) void k2_qkv(
    const float* __restrict__ feat_p, const float* __restrict__ fp_b,
    const float* __restrict__ lo_w, const float* __restrict__ lo_b,
    const float* __restrict__ hi_w, const float* __restrict__ hi_b,
    float* __restrict__ feat_c, float* __restrict__ qe,
    float* __restrict__ zz, float* __restrict__ kvout)
{
    __shared__ float lbuf[32][25];
    __shared__ float ske[32][33];
    __shared__ float svv[32][33];

    const int tid = threadIdx.x;
    const int r = tid >> 3;
    const int j = tid & 7;
    const int row = blockIdx.x * 32 + r;
    const int b = __builtin_amdgcn_readfirstlane((blockIdx.x * 32) / cN);
    const int n = row - b * cN;

    float f[cH];
    {
        const float4* f0 = (const float4*)(feat_p + (size_t)row * cH);
        const float4* f1 = (const float4*)(feat_p + (size_t)cROWS * cH + (size_t)row * cH);
        #pragma unroll
        for (int q = 0; q < 8; ++q) {
            float4 v0 = f0[q], v1 = f1[q];
            f[4*q]   = v0.x + v1.x + fp_b[4*q];
            f[4*q+1] = v0.y + v1.y + fp_b[4*q+1];
            f[4*q+2] = v0.z + v1.z + fp_b[4*q+2];
            f[4*q+3] = v0.w + v1.w + fp_b[4*q+3];
        }
    }
    // write combined feat (lane j writes chunk j)
    {
        float4 wc;
        wc.x = f[4*j]; wc.y = f[4*j+1]; wc.z = f[4*j+2]; wc.w = f[4*j+3];
        ((float4*)(feat_c + (size_t)row * cH))[j] = wc;
    }

    float lo0 = lo_b[j], lo1 = lo_b[j+8], lo2 = lo_b[j+16];
    #pragma unroll
    for (int i = 0; i < cH; ++i) {
        lo0 = fmaf(f[i], lo_w[j * cH + i], lo0);
        lo1 = fmaf(f[i], lo_w[(j+8) * cH + i], lo1);
        lo2 = fmaf(f[i], lo_w[(j+16) * cH + i], lo2);
    }
    lbuf[r][j] = lo0; lbuf[r][j+8] = lo1; lbuf[r][j+16] = lo2;
    __syncthreads();
    float lof[24];
    #pragma unroll
    for (int i = 0; i < 24; ++i) lof[i] = lbuf[r][i];

    float qv[4], kv4[4], vv4[4];
    #pragma unroll
    for (int m = 0; m < 4; ++m) {
        const int oi = m * 8 + j;
        float sq = hi_b[oi], sk = hi_b[32 + oi], sv = hi_b[64 + oi];
        #pragma unroll
        for (int i = 0; i < 24; ++i) {
            sq = fmaf(lof[i], hi_w[oi * 24 + i], sq);
            sk = fmaf(lof[i], hi_w[(32 + oi) * 24 + i], sk);
            sv = fmaf(lof[i], hi_w[(64 + oi) * 24 + i], sv);
        }
        qv[m] = elu1_(sq);
        kv4[m] = elu1_(sk);
        vv4[m] = sv;
    }

    float s0 = kv4[0], s1 = kv4[1], s2 = kv4[2], s3 = kv4[3];
    #pragma unroll
    for (int off = 1; off < 8; off <<= 1) {
        s0 += __shfl_xor(s0, off, 8);
        s1 += __shfl_xor(s1, off, 8);
        s2 += __shfl_xor(s2, off, 8);
        s3 += __shfl_xor(s3, off, 8);
    }
    if (j < 4) {
        float sv = (j == 0) ? s0 : ((j == 1) ? s1 : ((j == 2) ? s2 : s3));
        zz[(size_t)(b * cHEADS + j) * cN + n] = 1.0f / (sv + 1e-8f);
    }

    #pragma unroll
    for (int m = 0; m < 4; ++m) {
        qe[(size_t)row * cH + m * 8 + j] = qv[m];
        ske[r][m * 8 + j] = kv4[m];
        svv[r][m * 8 + j] = vv4[m];
    }
    __syncthreads();

    {
        const int m = tid >> 6, d = (tid >> 3) & 7, e = tid & 7;
        float s = 0.0f;
        #pragma unroll
        for (int rr = 0; rr < 32; ++rr)
            s = fmaf(ske[rr][m * 8 + d], svv[rr][m * 8 + e], s);
        atomicAdd(&kvout[(size_t)(b * cHEADS + m) * 64 + d * 8 + e], s);
    }
}

// K4: att_out + projections + GRU + blend. 8 lanes/row, 32 rows/block, grid 400.
__global__ __launch_bounds__(256) void k4_final(
    const float* __restrict__ x,
    const float* __restrict__ feat_c, const float* __restrict__ qe,
    const float* __restrict__ zz, const float* __restrict__ kv,
    const float* __restrict__ out_lo_w, const float* __restrict__ out_lo_b,
    const float* __restrict__ out_hi_w, const float* __restrict__ out_hi_b,
    const float* __restrict__ hp_w, const float* __restrict__ hp_b,
    const float* __restrict__ gru_wih, const float* __restrict__ gru_whh,
    const float* __restrict__ gru_bih, const float* __restrict__ gru_bhh,
    const float* __restrict__ op_w, const float* __restrict__ op_b,
    const float* __restrict__ log_decay,
    const float* __restrict__ rg1_w, const float* __restrict__ rg1_b,
    const float* __restrict__ rg2_w, const float* __restrict__ rg2_b,
    const float* __restrict__ log_reg,
    float* __restrict__ out)
{
    __shared__ float sA[32][36];
    __shared__ float sB[32][36];
    __shared__ float sC[32][36];

    const int tid = threadIdx.x;
    const int r = tid >> 3;
    const int j = tid & 7;
    const int row = blockIdx.x * 32 + r;
    const int b = __builtin_amdgcn_readfirstlane((blockIdx.x * 32) / cN);
    const int n = row - b * cN;

    {
        const float4* q4 = (const float4*)(qe + (size_t)row * cH);
        float4 v = q4[j];
        *(float4*)&sA[r][4 * j] = v;
    }
    __syncthreads();

    float o_m[4];
    #pragma unroll
    for (int m = 0; m < 4; ++m) {
        const float z = zz[(size_t)(b * cHEADS + m) * cN + n];
        const float* kvp = kv + (size_t)(b * cHEADS + m) * 64;
        float s = 0.0f;
        #pragma unroll
        for (int d = 0; d < 8; ++d)
            s = fmaf(sA[r][m * 8 + d], kvp[d * 8 + j], s);
        o_m[m] = s * z;
    }
    #pragma unroll
    for (int m = 0; m < 4; ++m) sB[r][m * 8 + j] = o_m[m];
    __syncthreads();

    float lo_j = out_lo_b[j];
    #pragma unroll
    for (int i = 0; i < cH; ++i)
        lo_j = fmaf(sB[r][i], out_lo_w[j * cH + i], lo_j);

    float lof[8];
    #pragma unroll
    for (int i = 0; i < 8; ++i) lof[i] = __shfl(lo_j, i, 8);

    float f2_m[4];
    #pragma unroll
    for (int m = 0; m < 4; ++m) {
        const int i = m * 8 + j;
        float s = out_hi_b[i];
        #pragma unroll
        for (int q = 0; q < 8; ++q) s = fmaf(lof[q], out_hi_w[i * 8 + q], s);
        f2_m[m] = feat_c[(size_t)row * cH + i] + s;
        sC[r][i] = f2_m[m];
    }
    __syncthreads();

    float h0_j = hp_b[j], g1_j = rg1_b[j];
    #pragma unroll
    for (int i = 0; i < cH; ++i) {
        float fv = sC[r][i];
        h0_j = fmaf(fv, hp_w[j * cH + i], h0_j);
        g1_j = fmaf(fv, rg1_w[j * cH + i], g1_j);
    }
    g1_j = fmaxf(0.0f, g1_j);

    float g1f[8];
    #pragma unroll
    for (int i = 0; i < 8; ++i) g1f[i] = __shfl(g1_j, i, 8);

    float ga = rg2_b[j], gb_ = rg2_b[8 + (j & 3)];
    #pragma unroll
    for (int q = 0; q < 8; ++q) {
        ga = fmaf(g1f[q], rg2_w[j * 8 + q], ga);
        gb_ = fmaf(g1f[q], rg2_w[(8 + (j & 3)) * 8 + q], gb_);
    }
    const float gate_a = sigmoidf_(ga);
    const float gate_b = sigmoidf_(gb_);

    const float last = x[(size_t)b * cT * cN + (size_t)(cT - 1) * cN + n];

    float whh_r[8], whh_z[8], whh_n[8], opw[8];
    #pragma unroll
    for (int i = 0; i < 8; ++i) {
        whh_r[i] = gru_whh[j * 8 + i];
        whh_z[i] = gru_whh[(8 + j) * 8 + i];
        whh_n[i] = gru_whh[(16 + j) * 8 + i];
        opw[i] = op_w[i];
    }
    const float wih_r = gru_wih[j], wih_z = gru_wih[8 + j], wih_n = gru_wih[16 + j];
    const float bih_r = gru_bih[j], bih_z = gru_bih[8 + j], bih_n = gru_bih[16 + j];
    const float bhh_r = gru_bhh[j], bhh_z = gru_bhh[8 + j], bhh_n = gru_bhh[16 + j];
    const float opb = op_b[0];

    float h_full[8];
    #pragma unroll
    for (int i = 0; i < 8; ++i) h_full[i] = __shfl(h0_j, i, 8);
    float h_own = h0_j;
    float cur = last;
    float po_a = 0.0f, po_b = 0.0f;

    #pragma unroll
    for (int s = 0; s < cHOR; ++s) {
        float ghr = bhh_r, ghz = bhh_z, ghn = bhh_n;
        #pragma unroll
        for (int i = 0; i < 8; ++i) {
            ghr = fmaf(h_full[i], whh_r[i], ghr);
            ghz = fmaf(h_full[i], whh_z[i], ghz);
            ghn = fmaf(h_full[i], whh_n[i], ghn);
        }
        const float r_ = sigmoidf_(fmaf(wih_r, cur, bih_r) + ghr);
        const float zg = sigmoidf_(fmaf(wih_z, cur, bih_z) + ghz);
        const float nn = tanhf_(fmaf(wih_n, cur, bih_n) + r_ * ghn);
        const float hn = (1.0f - zg) * nn + zg * h_own;
        h_own = hn;
        #pragma unroll
        for (int i = 0; i < 8; ++i) h_full[i] = __shfl(hn, i, 8);
        float p = opb;
        #pragma unroll
        for (int i = 0; i < 8; ++i) p = fmaf(h_full[i], opw[i], p);
        po_a = (s == j) ? p : po_a;
        po_b = (s == 8 + j) ? p : po_b;
        cur = p;
    }

    const float dk = __expf(log_decay[0]);
    float* orow = out + (size_t)row * 12;
    orow[j] = gate_a * po_a + (1.0f - gate_a) * last * __expf(-dk * (float)(j + 1));
    if (j < 4)
        orow[8 + j] = gate_b * po_b + (1.0f - gate_b) * last * __expf(-dk * (float)(j + 9));

    if (row == 0 && j == 0)
        out[(size_t)cROWS * 12] = __expf(log_reg[0]) * (1.0f / (float)cN);
}

extern "C" void kernel_launch(void* const* d_in, const int* in_sizes, int n_in,
                              void* d_out, int out_size, void* d_ws, size_t ws_size,
                              hipStream_t stream)
{
    const float* x      = (const float*)d_in[0];
    const float* dw_w   = (const float*)d_in[1];
    const float* dw_b   = (const float*)d_in[2];
    const float* bn1_g  = (const float*)d_in[3];
    const float* bn1_b  = (const float*)d_in[4];
    const float* bn1_m  = (const float*)d_in[5];
    const float* bn1_v  = (const float*)d_in[6];
    const float* pw_w   = (const float*)d_in[7];
    const float* pw_b   = (const float*)d_in[8];
    const float* bn2_g  = (const float*)d_in[9];
    const float* bn2_b  = (const float*)d_in[10];
    const float* bn2_m  = (const float*)d_in[11];
    const float* bn2_v  = (const float*)d_in[12];
    const float* fp_w   = (const float*)d_in[13];
    const float* fp_b   = (const float*)d_in[14];
    const float* lo_w   = (const float*)d_in[15];
    const float* lo_b   = (const float*)d_in[16];
    const float* hi_w   = (const float*)d_in[17];
    const float* hi_b   = (const float*)d_in[18];
    const float* olo_w  = (const float*)d_in[19];
    const float* olo_b  = (const float*)d_in[20];
    const float* ohi_w  = (const float*)d_in[21];
    const float* ohi_b  = (const float*)d_in[22];
    // d_in[23]=u, d_in[24]=v dead (softmax row-sums == 1 -> mean|attn| == 1/N)
    const float* log_reg = (const float*)d_in[25];
    const float* hp_w   = (const float*)d_in[26];
    const float* hp_b   = (const float*)d_in[27];
    const float* gru_wih = (const float*)d_in[28];
    const float* gru_whh = (const float*)d_in[29];
    const float* gru_bih = (const float*)d_in[30];
    const float* gru_bhh = (const float*)d_in[31];
    const float* op_w   = (const float*)d_in[32];
    const float* op_b   = (const float*)d_in[33];
    const float* log_decay = (const float*)d_in[34];
    const float* rg1_w  = (const float*)d_in[35];
    const float* rg1_b  = (const float*)d_in[36];
    const float* rg2_w  = (const float*)d_in[37];
    const float* rg2_b  = (const float*)d_in[38];

    float* ws = (float*)d_ws;
    unsigned short* wbt = (unsigned short*)ws;     // 32768 bf16 = 16384 float slots
    float* feat_p = ws + 16384;                    // 2 x 409600   [hk][row*32+h]
    float* feat_c = feat_p + 2 * 409600;           // 409600       [row*32+h] (incl fp_b)
    float* qe     = feat_c + 409600;               // 409600
    float* zz     = qe + 409600;                   // 51200
    float* kv     = zz + 51200;                    // 2048

    k0_init<<<128, 256, 0, stream>>>(fp_w, wbt, kv);
    kFeat<<<1600, 64, 0, stream>>>(x, dw_w, dw_b, bn1_g, bn1_b, bn1_m, bn1_v,
                                   pw_w, pw_b, bn2_g, bn2_b, bn2_m, bn2_v,
                                   wbt, feat_p);
    k2_qkv<<<cROWS / 32, 256, 0, stream>>>(feat_p, fp_b, lo_w, lo_b, hi_w, hi_b,
                                           feat_c, qe, zz, kv);
    k4_final<<<cROWS / 32, 256, 0, stream>>>(x, feat_c, qe, zz, kv,
                                             olo_w, olo_b, ohi_w, ohi_b,
                                             hp_w, hp_b, gru_wih, gru_whh, gru_bih, gru_bhh,
                                             op_w, op_b, log_decay,
                                             rg1_w, rg1_b, rg2_w, rg2_b, log_reg,
                                             (float*)d_out);
}